// Round 15
// baseline (1738.690 us; speedup 1.0000x reference)
//
#include <hip/hip_runtime.h>
#include <hip/hip_bf16.h>
#include <cstdint>

#define VOCAB 28996
#define T_STEPS 1024
#define D_IN 256
#define HDIM 512

using f32x4 = __attribute__((ext_vector_type(4))) float;
using s16x8 = __attribute__((ext_vector_type(8))) short;

static __device__ __forceinline__ unsigned short f2bf(float f){
    unsigned u = __float_as_uint(f);
    u = u + 0x7FFFu + ((u >> 16) & 1u);   // round-to-nearest-even
    return (unsigned short)(u >> 16);
}

#define SENT_U 0x7FC00001u

// ---------------------------------------------------------------------------
// Kernel 1: init — hs row 0 = h0, rows 1..1024 = NaN sentinel; zero rank ctrs
// ---------------------------------------------------------------------------
__global__ void init_hs_kernel(const float* __restrict__ h0, float* __restrict__ hs,
                               unsigned* __restrict__ ctrl){
    const int col = threadIdx.x;          // 0..511
    const int row = blockIdx.x;           // 0..1024
    float v = (row == 0) ? h0[col] : __uint_as_float(SENT_U);
    hs[(size_t)row * HDIM + col] = v;
    if (row == 0 && col < 8) ctrl[col] = 0u;
}

// ---------------------------------------------------------------------------
// Kernel 2: xg = x @ w_ih^T + b_ih   ([1024 x 256] @ [256 -> 1536])  fp32
// ---------------------------------------------------------------------------
__global__ void xg_kernel(const float* __restrict__ x, const float* __restrict__ w_ih,
                          const float* __restrict__ b_ih, float* __restrict__ xg){
    __shared__ float xs[8][D_IN];
    const int tid = threadIdx.x;
    const int i   = blockIdx.x * 256 + tid;   // 0..1535
    const int t0  = blockIdx.y * 8;
    #pragma unroll
    for (int r = 0; r < 8; ++r)
        xs[r][tid] = x[(size_t)(t0 + r) * D_IN + tid];
    __syncthreads();

    float acc[8] = {0.f,0.f,0.f,0.f,0.f,0.f,0.f,0.f};
    const float* wrow = w_ih + (size_t)i * D_IN;
    for (int d = 0; d < D_IN; d += 4){
        float4 w4 = *(const float4*)(wrow + d);
        #pragma unroll
        for (int r = 0; r < 8; ++r){
            acc[r] += w4.x * xs[r][d]   + w4.y * xs[r][d+1]
                    + w4.z * xs[r][d+2] + w4.w * xs[r][d+3];
        }
    }
    const float b = b_ih[i];
    #pragma unroll
    for (int r = 0; r < 8; ++r)
        xg[(size_t)(t0 + r) * (3*HDIM) + i] = acc[r] + b;
}

// ---------------------------------------------------------------------------
// Kernel 3: GRU scan — r14 (best: 1.44us/step) + single-poller LDS relay.
// Diagnosis r14: 256 waves/XCD x 2KB NT-poll per round saturates L2 read BW
// (~500KB/round) -> inflated RTT + max-of-256-chains jitter sets each step.
// Fix: ONLY wave 0 of each WG polls the row (8x less poll traffic), stages
// into parity double-buffered LDS, raises LDS step-flag; waves 1..7 ds-spin
// (zero L2 traffic). Double-buffer race-free by monotonicity: row t+1
// complete => every wave finished step t => no live readers of buf (t+1)&1.
// Kept from r14: 48 resident weight fp32/thread (waves_per_eu(2,2), VGPR=88
// spill-free), NT-poll semantics (no L1 allocate -> always-fresh L2 read),
// write-through store IS the flag, end-of-loop vmcnt(0) drain, xg decouple.
// Redundant per-XCD clusters; dead clusters exit via bounded timeout ->
// sh_step=MAX; >=1 complete cluster by pigeonhole; identical writes benign.
// ---------------------------------------------------------------------------
#define LDW(G, P, s) \
    float G##s##0 = (P)[128*s + 0], G##s##1 = (P)[128*s + 1], \
          G##s##2 = (P)[128*s + 2], G##s##3 = (P)[128*s + 3];
#define PINW(G, s) \
    asm volatile("" : "+v"(G##s##0), "+v"(G##s##1), "+v"(G##s##2), "+v"(G##s##3));

#define GSTEP(s) { \
    float4 h4 = *(const float4*)&hcur[4*c + 128*s]; \
    ar += R##s##0*h4.x + R##s##1*h4.y + R##s##2*h4.z + R##s##3*h4.w; \
    az += Z##s##0*h4.x + Z##s##1*h4.y + Z##s##2*h4.z + Z##s##3*h4.w; \
    an += N##s##0*h4.x + N##s##1*h4.y + N##s##2*h4.z + N##s##3*h4.w; }

__launch_bounds__(512)
__attribute__((amdgpu_waves_per_eu(2, 2)))
__global__ void scan_kernel(const float* __restrict__ xg, const float* __restrict__ w_hh,
                            const float* __restrict__ b_hh, float* hs, unsigned* ctrl){
    __shared__ __align__(16) float hbuf[2][HDIM];   // parity double-buffer (4KB)
    __shared__ unsigned sh_rank;
    __shared__ int sh_step;

    const int tid = threadIdx.x;
    if (tid == 0){
        unsigned xcc;
        asm volatile("s_getreg_b32 %0, hwreg(HW_REG_XCC_ID)" : "=s"(xcc));
        sh_rank = __hip_atomic_fetch_add(&ctrl[xcc & 7u], 1u, __ATOMIC_RELAXED,
                                         __HIP_MEMORY_SCOPE_AGENT);
        sh_step = -1;
    }
    __syncthreads();
    const unsigned rank = sh_rank;
    if (rank >= 32u) return;              // uniform per WG

    const int wv   = tid >> 6;            // wave 0..7
    const int lane = tid & 63;
    const int c    = tid & 31;            // column-chunk selector 0..31
    const int jl   = tid >> 5;            // 0..15
    const int j    = (int)rank * 16 + jl; // 0..511

    // -- recurrent weights: 48 floats/thread -> resident VGPRs (r14-proven) --
    const float* wrp = w_hh + (size_t)j * HDIM + 4*c;
    const float* wzp = w_hh + (size_t)(HDIM   + j) * HDIM + 4*c;
    const float* wnp = w_hh + (size_t)(2*HDIM + j) * HDIM + 4*c;
    LDW(R, wrp, 0) LDW(R, wrp, 1) LDW(R, wrp, 2) LDW(R, wrp, 3)
    LDW(Z, wzp, 0) LDW(Z, wzp, 1) LDW(Z, wzp, 2) LDW(Z, wzp, 3)
    LDW(N, wnp, 0) LDW(N, wnp, 1) LDW(N, wnp, 2) LDW(N, wnp, 3)
    PINW(R,0) PINW(R,1) PINW(R,2) PINW(R,3)
    PINW(Z,0) PINW(Z,1) PINW(Z,2) PINW(Z,3)
    PINW(N,0) PINW(N,1) PINW(N,2) PINW(N,3)

    float bhr = b_hh[j], bhz = b_hh[HDIM + j], bhn = b_hh[2*HDIM + j];
    asm volatile("" : "+v"(bhr), "+v"(bhz), "+v"(bhn));

    // xg pipeline register (t=0 filled here, re-filled each step)
    float xr_c = 0.f, xz_c = 0.f, xn_c = 0.f;
    if (c == 0){ xr_c = xg[j]; xz_c = xg[HDIM + j]; xn_c = xg[2*HDIM + j]; }

    #pragma unroll 1
    for (int t = 0; t < T_STEPS; ++t){
        float* hcur = hbuf[t & 1];

        if (wv == 0){
            // ---- wave 0: NT-poll row t (64 lanes x 32B = full 2KB row) ----
            const float4* myp = (const float4*)(hs + (size_t)t * HDIM) + lane;
            float4 va, vb;
            int spins = 0, dead = 0;
            for (;;){
                asm volatile("global_load_dwordx4 %0, %2, off nt\n\t"
                             "global_load_dwordx4 %1, %2, off offset:1024 nt\n\t"
                             "s_waitcnt vmcnt(0)"
                             : "=&v"(va), "=&v"(vb) : "v"(myp) : "memory");
                int ok = (__float_as_uint(va.x) != SENT_U) & (__float_as_uint(va.y) != SENT_U)
                       & (__float_as_uint(va.z) != SENT_U) & (__float_as_uint(va.w) != SENT_U)
                       & (__float_as_uint(vb.x) != SENT_U) & (__float_as_uint(vb.y) != SENT_U)
                       & (__float_as_uint(vb.z) != SENT_U) & (__float_as_uint(vb.w) != SENT_U);
                if (__all(ok)) break;     // wave-uniform
                if (++spins > 5000){ dead = 1; break; }
            }
            if (dead){
                if (lane == 0)
                    __hip_atomic_store(&sh_step, 0x7FFFFFFF, __ATOMIC_RELAXED,
                                       __HIP_MEMORY_SCOPE_WORKGROUP);
                return;
            }
            // stage into the parity buffer, then raise the flag
            *(float4*)&hcur[4 * lane]       = va;
            *(float4*)&hcur[256 + 4 * lane] = vb;
            asm volatile("s_waitcnt lgkmcnt(0)" ::: "memory");
            if (lane == 0)
                __hip_atomic_store(&sh_step, t, __ATOMIC_RELAXED,
                                   __HIP_MEMORY_SCOPE_WORKGROUP);
        } else {
            // ---- waves 1..7: ds-spin on the step flag (no L2 traffic) ----
            int v;
            do {
                v = __hip_atomic_load(&sh_step, __ATOMIC_RELAXED,
                                      __HIP_MEMORY_SCOPE_WORKGROUP);
            } while (v < t);
            if (v == 0x7FFFFFFF) return;
        }
        asm volatile("" ::: "memory");
        __builtin_amdgcn_sched_barrier(0);

        // ---- issue next step's xg loads (landed by end-of-loop vmcnt) ----
        float xr_n = 0.f, xz_n = 0.f, xn_n = 0.f;
        if (c == 0 && t + 1 < T_STEPS){
            const float* xgn = xg + (size_t)(t + 1) * (3*HDIM);
            xr_n = xgn[j]; xz_n = xgn[HDIM + j]; xn_n = xgn[2*HDIM + j];
        }

        // ---- partial matvec: 48 FMAs/lane, 3 chains; reduce over c=0..31 ----
        float ar = 0.f, az = 0.f, an = 0.f;
        GSTEP(0) GSTEP(1) GSTEP(2) GSTEP(3)
        #pragma unroll
        for (int m = 1; m < 32; m <<= 1){
            ar += __shfl_xor(ar, m);
            az += __shfl_xor(az, m);
            an += __shfl_xor(an, m);
        }

        if (c == 0){
            const float r  = 1.0f / (1.0f + __expf(-(xr_c + ar + bhr)));
            const float z  = 1.0f / (1.0f + __expf(-(xz_c + az + bhz)));
            const float nn = xn_c + r * (an + bhn);
            const float e  = __expf(2.0f * nn);
            const float th = 1.0f - 2.0f / (e + 1.0f);   // tanh, inf-safe
            const float hnew = (1.0f - z) * th + z * hcur[j];
            hs[(size_t)(t + 1) * HDIM + j] = hnew;   // write-through store IS the flag
        }
        // drain the h-store to L2 NOW (visibility clock starts in our slack)
        // and land the xg prefetch so the next poll inherits nothing.
        asm volatile("s_waitcnt vmcnt(0)" ::: "memory");

        xr_c = xr_n; xz_c = xz_n; xn_c = xn_n;
    }
}

// ---------------------------------------------------------------------------
// Kernel 4: preds = hs[1..1024] @ w_pred^T + b_pred  (bf16 MFMA, fp32 out)
// ---------------------------------------------------------------------------
__launch_bounds__(256)
__global__ void pred_gemm_kernel(const float* __restrict__ hs, const float* __restrict__ w_pred,
                                 const float* __restrict__ b_pred, float* __restrict__ out){
    __shared__ unsigned short As[128 * 32];
    __shared__ unsigned short Bs[128 * 32];
    const int tid   = threadIdx.x;
    const int mtile = blockIdx.x;    // 0..7
    const int ntile = blockIdx.y;    // 0..226
    const int row  = tid >> 1, half = tid & 1;
    const int wave = tid >> 6, lane = tid & 63;
    const int wm = wave >> 1, wn = wave & 1;
    const int lr = lane & 15, kq = lane >> 4;

    f32x4 acc[4][4] = {};

    const float* Abase = hs + HDIM /*skip h0 row*/ + (size_t)(mtile * 128 + row) * HDIM;
    const int    nrow  = ntile * 128 + row;
    const float* Bbase = w_pred + (size_t)nrow * HDIM;

    for (int k0 = 0; k0 < HDIM; k0 += 32){
        {
            const float* srcp = Abase + k0 + half * 16;
            unsigned short* dst = &As[row * 32 + half * 16];
            #pragma unroll
            for (int q = 0; q < 4; ++q){
                float4 v = *(const float4*)(srcp + 4 * q);
                uint2 p;
                p.x = (unsigned)f2bf(v.x) | ((unsigned)f2bf(v.y) << 16);
                p.y = (unsigned)f2bf(v.z) | ((unsigned)f2bf(v.w) << 16);
                *(uint2*)(dst + 4 * q) = p;
            }
        }
        {
            unsigned short* dst = &Bs[row * 32 + half * 16];
            if (nrow < VOCAB){
                const float* srcp = Bbase + k0 + half * 16;
                #pragma unroll
                for (int q = 0; q < 4; ++q){
                    float4 v = *(const float4*)(srcp + 4 * q);
                    uint2 p;
                    p.x = (unsigned)f2bf(v.x) | ((unsigned)f2bf(v.y) << 16);
                    p.y = (unsigned)f2bf(v.z) | ((unsigned)f2bf(v.w) << 16);
                    *(uint2*)(dst + 4 * q) = p;
                }
            } else {
                uint2 zz; zz.x = 0u; zz.y = 0u;
                #pragma unroll
                for (int q = 0; q < 4; ++q) *(uint2*)(dst + 4 * q) = zz;
            }
        }
        __syncthreads();

        const unsigned short* Ab = &As[(wm * 64 + lr) * 32 + kq * 8];
        const unsigned short* Bb = &Bs[(wn * 64 + lr) * 32 + kq * 8];
        s16x8 af[4], bf[4];
        #pragma unroll
        for (int mf = 0; mf < 4; ++mf) af[mf] = *(const s16x8*)(Ab + mf * 16 * 32);
        #pragma unroll
        for (int nf = 0; nf < 4; ++nf) bf[nf] = *(const s16x8*)(Bb + nf * 16 * 32);
        #pragma unroll
        for (int mf = 0; mf < 4; ++mf){
            #pragma unroll
            for (int nf = 0; nf < 4; ++nf){
                acc[mf][nf] = __builtin_amdgcn_mfma_f32_16x16x32_bf16(af[mf], bf[nf], acc[mf][nf], 0, 0, 0);
            }
        }
        __syncthreads();
    }

    #pragma unroll
    for (int nf = 0; nf < 4; ++nf){
        const int n = ntile * 128 + wn * 64 + nf * 16 + lr;
        if (n >= VOCAB) continue;
        const float bp = b_pred[n];
        #pragma unroll
        for (int mf = 0; mf < 4; ++mf){
            const int m = mtile * 128 + wm * 64 + mf * 16 + kq * 4;
            #pragma unroll
            for (int q = 0; q < 4; ++q){
                out[(size_t)(m + q) * VOCAB + n] = acc[mf][nf][q] + bp;
            }
        }
    }
}

// ---------------------------------------------------------------------------
extern "C" void kernel_launch(void* const* d_in, const int* in_sizes, int n_in,
                              void* d_out, int out_size, void* d_ws, size_t ws_size,
                              hipStream_t stream){
    const float* x      = (const float*)d_in[0];
    const float* h0     = (const float*)d_in[1];
    const float* w_ih   = (const float*)d_in[2];
    const float* w_hh   = (const float*)d_in[3];
    const float* b_ih   = (const float*)d_in[4];
    const float* b_hh   = (const float*)d_in[5];
    const float* w_pred = (const float*)d_in[6];
    const float* b_pred = (const float*)d_in[7];
    float* out = (float*)d_out;

    float*    xg   = (float*)d_ws;                        // 1024*1536 fp32
    float*    hs   = xg + (size_t)T_STEPS * (3*HDIM);     // 1025*512  fp32
    unsigned* ctrl = (unsigned*)(hs + (size_t)(T_STEPS+1) * HDIM);  // 8 u32

    hipLaunchKernelGGL(init_hs_kernel, dim3(T_STEPS + 1), dim3(HDIM), 0, stream, h0, hs, ctrl);
    hipLaunchKernelGGL(xg_kernel,      dim3(6, 128),      dim3(256),  0, stream, x, w_ih, b_ih, xg);
    hipLaunchKernelGGL(scan_kernel,    dim3(256),         dim3(512),  0, stream, xg, w_hh, b_hh, hs, ctrl);
    hipLaunchKernelGGL(pred_gemm_kernel, dim3(8, 227),    dim3(256),  0, stream, hs, w_pred, b_pred, out);
}

// Round 16
// 1548.175 us; speedup vs baseline: 1.1231x; 1.1231x over previous
//
#include <hip/hip_runtime.h>
#include <hip/hip_bf16.h>
#include <cstdint>

#define VOCAB 28996
#define T_STEPS 1024
#define D_IN 256
#define HDIM 512

using f32x4 = __attribute__((ext_vector_type(4))) float;
using s16x8 = __attribute__((ext_vector_type(8))) short;

static __device__ __forceinline__ unsigned short f2bf(float f){
    unsigned u = __float_as_uint(f);
    u = u + 0x7FFFu + ((u >> 16) & 1u);   // round-to-nearest-even
    return (unsigned short)(u >> 16);
}

#define SENT_U 0x7FC00001u

// ---------------------------------------------------------------------------
// Kernel 1: init — hs row 0 = h0, rows 1..1024 = NaN sentinel; zero rank ctrs
// ---------------------------------------------------------------------------
__global__ void init_hs_kernel(const float* __restrict__ h0, float* __restrict__ hs,
                               unsigned* __restrict__ ctrl){
    const int col = threadIdx.x;          // 0..511
    const int row = blockIdx.x;           // 0..1024
    float v = (row == 0) ? h0[col] : __uint_as_float(SENT_U);
    hs[(size_t)row * HDIM + col] = v;
    if (row == 0 && col < 8) ctrl[col] = 0u;
}

// ---------------------------------------------------------------------------
// Kernel 2: xg = x @ w_ih^T + b_ih   ([1024 x 256] @ [256 -> 1536])  fp32
// ---------------------------------------------------------------------------
__global__ void xg_kernel(const float* __restrict__ x, const float* __restrict__ w_ih,
                          const float* __restrict__ b_ih, float* __restrict__ xg){
    __shared__ float xs[8][D_IN];
    const int tid = threadIdx.x;
    const int i   = blockIdx.x * 256 + tid;   // 0..1535
    const int t0  = blockIdx.y * 8;
    #pragma unroll
    for (int r = 0; r < 8; ++r)
        xs[r][tid] = x[(size_t)(t0 + r) * D_IN + tid];
    __syncthreads();

    float acc[8] = {0.f,0.f,0.f,0.f,0.f,0.f,0.f,0.f};
    const float* wrow = w_ih + (size_t)i * D_IN;
    for (int d = 0; d < D_IN; d += 4){
        float4 w4 = *(const float4*)(wrow + d);
        #pragma unroll
        for (int r = 0; r < 8; ++r){
            acc[r] += w4.x * xs[r][d]   + w4.y * xs[r][d+1]
                    + w4.z * xs[r][d+2] + w4.w * xs[r][d+3];
        }
    }
    const float b = b_ih[i];
    #pragma unroll
    for (int r = 0; r < 8; ++r)
        xg[(size_t)(t0 + r) * (3*HDIM) + i] = acc[r] + b;
}

// ---------------------------------------------------------------------------
// Kernel 3: GRU scan — r14 (best measured: 1.44us/step) minus the trailing
// store-drain. Rationale: the end-of-loop s_waitcnt vmcnt(0) blocked the
// producer wave on its own h-store acknowledgment (~200-300cy/step) — but a
// posted store reaches L2 at the same speed without the block. The next
// poll's INTERNAL vmcnt(0) (first round) now absorbs both the store-ack and
// the xg-prefetch lands, overlapped with the poll-load latency instead of
// serialized before it. r15's single-poller relay regressed (poll traffic
// was not the limiter) -> all-wave direct poll retained.
// Everything else r14-identical:
//  * 32-WG clusters x 512 thr, 16 j/WG, 32 thr/j, 48 weight fp32/thread
//    resident in VGPRs (waves_per_eu(2,2), VGPR=88 spill-free).
//  * all-wave NT-poll of the sentinel row (nt = no L1 allocate -> fresh
//    XCD-L2 read), per-wave LDS stage, write-through store IS the flag.
//  * zero atomics/barriers in the loop; redundant per-XCD clusters; dead
//    clusters exit on bounded wave-uniform timeout; >=1 complete cluster by
//    pigeonhole; identical writes -> benign races.
// ---------------------------------------------------------------------------
#define LDW(G, P, s) \
    float G##s##0 = (P)[128*s + 0], G##s##1 = (P)[128*s + 1], \
          G##s##2 = (P)[128*s + 2], G##s##3 = (P)[128*s + 3];
#define PINW(G, s) \
    asm volatile("" : "+v"(G##s##0), "+v"(G##s##1), "+v"(G##s##2), "+v"(G##s##3));

#define GSTEP(s) { \
    float4 h4 = *(const float4*)&hbuf[wv][4*c + 128*s]; \
    ar += R##s##0*h4.x + R##s##1*h4.y + R##s##2*h4.z + R##s##3*h4.w; \
    az += Z##s##0*h4.x + Z##s##1*h4.y + Z##s##2*h4.z + Z##s##3*h4.w; \
    an += N##s##0*h4.x + N##s##1*h4.y + N##s##2*h4.z + N##s##3*h4.w; }

__launch_bounds__(512)
__attribute__((amdgpu_waves_per_eu(2, 2)))
__global__ void scan_kernel(const float* __restrict__ xg, const float* __restrict__ w_hh,
                            const float* __restrict__ b_hh, float* hs, unsigned* ctrl){
    __shared__ __align__(16) float hbuf[8][HDIM];   // per-wave private row copy
    __shared__ unsigned sh_rank;

    const int tid = threadIdx.x;
    if (tid == 0){
        unsigned xcc;
        asm volatile("s_getreg_b32 %0, hwreg(HW_REG_XCC_ID)" : "=s"(xcc));
        sh_rank = __hip_atomic_fetch_add(&ctrl[xcc & 7u], 1u, __ATOMIC_RELAXED,
                                         __HIP_MEMORY_SCOPE_AGENT);
    }
    __syncthreads();
    const unsigned rank = sh_rank;
    if (rank >= 32u) return;              // uniform per WG

    const int wv   = tid >> 6;            // wave 0..7
    const int lane = tid & 63;
    const int c    = tid & 31;            // column-chunk selector 0..31
    const int jl   = tid >> 5;            // 0..15
    const int j    = (int)rank * 16 + jl; // 0..511

    // -- recurrent weights: 48 floats/thread -> resident VGPRs (r14-proven) --
    const float* wrp = w_hh + (size_t)j * HDIM + 4*c;
    const float* wzp = w_hh + (size_t)(HDIM   + j) * HDIM + 4*c;
    const float* wnp = w_hh + (size_t)(2*HDIM + j) * HDIM + 4*c;
    LDW(R, wrp, 0) LDW(R, wrp, 1) LDW(R, wrp, 2) LDW(R, wrp, 3)
    LDW(Z, wzp, 0) LDW(Z, wzp, 1) LDW(Z, wzp, 2) LDW(Z, wzp, 3)
    LDW(N, wnp, 0) LDW(N, wnp, 1) LDW(N, wnp, 2) LDW(N, wnp, 3)
    PINW(R,0) PINW(R,1) PINW(R,2) PINW(R,3)
    PINW(Z,0) PINW(Z,1) PINW(Z,2) PINW(Z,3)
    PINW(N,0) PINW(N,1) PINW(N,2) PINW(N,3)

    float bhr = b_hh[j], bhz = b_hh[HDIM + j], bhn = b_hh[2*HDIM + j];
    asm volatile("" : "+v"(bhr), "+v"(bhz), "+v"(bhn));

    // xg pipeline register (t=0 filled here, re-filled each step)
    float xr_c = 0.f, xz_c = 0.f, xn_c = 0.f;
    if (c == 0){ xr_c = xg[j]; xz_c = xg[HDIM + j]; xn_c = xg[2*HDIM + j]; }

    #pragma unroll 1
    for (int t = 0; t < T_STEPS; ++t){
        // ---- detect h_t ready: NT-poll the row itself (detect == stage).
        // First round's vmcnt(0) also absorbs last step's store-ack and the
        // xg prefetch lands (overlapped with the poll-load latency).
        const float4* myp = (const float4*)(hs + (size_t)t * HDIM) + lane;
        float4 va, vb;
        int spins = 0;
        for (;;){
            asm volatile("global_load_dwordx4 %0, %2, off nt\n\t"
                         "global_load_dwordx4 %1, %2, off offset:1024 nt\n\t"
                         "s_waitcnt vmcnt(0)"
                         : "=&v"(va), "=&v"(vb) : "v"(myp) : "memory");
            int ok = (__float_as_uint(va.x) != SENT_U) & (__float_as_uint(va.y) != SENT_U)
                   & (__float_as_uint(va.z) != SENT_U) & (__float_as_uint(va.w) != SENT_U)
                   & (__float_as_uint(vb.x) != SENT_U) & (__float_as_uint(vb.y) != SENT_U)
                   & (__float_as_uint(vb.z) != SENT_U) & (__float_as_uint(vb.w) != SENT_U);
            if (__all(ok)) break;         // wave-uniform
            if (++spins > 5000) return;   // wave-uniform timeout (dead cluster)
        }

        // ---- issue next step's xg loads (land inside next poll's vmcnt) ----
        float xr_n = 0.f, xz_n = 0.f, xn_n = 0.f;
        if (c == 0 && t + 1 < T_STEPS){
            const float* xgn = xg + (size_t)(t + 1) * (3*HDIM);
            xr_n = xgn[j]; xz_n = xgn[HDIM + j]; xn_n = xgn[2*HDIM + j];
        }

        // ---- stage to this wave's LDS row (contiguous 16B/lane) ----
        *(float4*)&hbuf[wv][4 * lane]       = va;
        *(float4*)&hbuf[wv][256 + 4 * lane] = vb;
        asm volatile("s_waitcnt lgkmcnt(0)" ::: "memory");
        __builtin_amdgcn_sched_barrier(0);

        // ---- partial matvec: 48 FMAs/lane, 3 chains; reduce over c=0..31 ----
        float ar = 0.f, az = 0.f, an = 0.f;
        GSTEP(0) GSTEP(1) GSTEP(2) GSTEP(3)
        #pragma unroll
        for (int m = 1; m < 32; m <<= 1){
            ar += __shfl_xor(ar, m);
            az += __shfl_xor(az, m);
            an += __shfl_xor(an, m);
        }

        if (c == 0){
            const float r  = 1.0f / (1.0f + __expf(-(xr_c + ar + bhr)));
            const float z  = 1.0f / (1.0f + __expf(-(xz_c + az + bhz)));
            const float nn = xn_c + r * (an + bhn);
            const float e  = __expf(2.0f * nn);
            const float th = 1.0f - 2.0f / (e + 1.0f);   // tanh, inf-safe
            const float hnew = (1.0f - z) * th + z * hbuf[wv][j];
            hs[(size_t)(t + 1) * HDIM + j] = hnew;   // posted store IS the flag
        }
        // no trailing drain: the store propagates to L2 on its own; its ack
        // (and the xg lands) are absorbed by the next poll's vmcnt(0).

        xr_c = xr_n; xz_c = xz_n; xn_c = xn_n;
    }
}

// ---------------------------------------------------------------------------
// Kernel 4: preds = hs[1..1024] @ w_pred^T + b_pred  (bf16 MFMA, fp32 out)
// ---------------------------------------------------------------------------
__launch_bounds__(256)
__global__ void pred_gemm_kernel(const float* __restrict__ hs, const float* __restrict__ w_pred,
                                 const float* __restrict__ b_pred, float* __restrict__ out){
    __shared__ unsigned short As[128 * 32];
    __shared__ unsigned short Bs[128 * 32];
    const int tid   = threadIdx.x;
    const int mtile = blockIdx.x;    // 0..7
    const int ntile = blockIdx.y;    // 0..226
    const int row  = tid >> 1, half = tid & 1;
    const int wave = tid >> 6, lane = tid & 63;
    const int wm = wave >> 1, wn = wave & 1;
    const int lr = lane & 15, kq = lane >> 4;

    f32x4 acc[4][4] = {};

    const float* Abase = hs + HDIM /*skip h0 row*/ + (size_t)(mtile * 128 + row) * HDIM;
    const int    nrow  = ntile * 128 + row;
    const float* Bbase = w_pred + (size_t)nrow * HDIM;

    for (int k0 = 0; k0 < HDIM; k0 += 32){
        {
            const float* srcp = Abase + k0 + half * 16;
            unsigned short* dst = &As[row * 32 + half * 16];
            #pragma unroll
            for (int q = 0; q < 4; ++q){
                float4 v = *(const float4*)(srcp + 4 * q);
                uint2 p;
                p.x = (unsigned)f2bf(v.x) | ((unsigned)f2bf(v.y) << 16);
                p.y = (unsigned)f2bf(v.z) | ((unsigned)f2bf(v.w) << 16);
                *(uint2*)(dst + 4 * q) = p;
            }
        }
        {
            unsigned short* dst = &Bs[row * 32 + half * 16];
            if (nrow < VOCAB){
                const float* srcp = Bbase + k0 + half * 16;
                #pragma unroll
                for (int q = 0; q < 4; ++q){
                    float4 v = *(const float4*)(srcp + 4 * q);
                    uint2 p;
                    p.x = (unsigned)f2bf(v.x) | ((unsigned)f2bf(v.y) << 16);
                    p.y = (unsigned)f2bf(v.z) | ((unsigned)f2bf(v.w) << 16);
                    *(uint2*)(dst + 4 * q) = p;
                }
            } else {
                uint2 zz; zz.x = 0u; zz.y = 0u;
                #pragma unroll
                for (int q = 0; q < 4; ++q) *(uint2*)(dst + 4 * q) = zz;
            }
        }
        __syncthreads();

        const unsigned short* Ab = &As[(wm * 64 + lr) * 32 + kq * 8];
        const unsigned short* Bb = &Bs[(wn * 64 + lr) * 32 + kq * 8];
        s16x8 af[4], bf[4];
        #pragma unroll
        for (int mf = 0; mf < 4; ++mf) af[mf] = *(const s16x8*)(Ab + mf * 16 * 32);
        #pragma unroll
        for (int nf = 0; nf < 4; ++nf) bf[nf] = *(const s16x8*)(Bb + nf * 16 * 32);
        #pragma unroll
        for (int mf = 0; mf < 4; ++mf){
            #pragma unroll
            for (int nf = 0; nf < 4; ++nf){
                acc[mf][nf] = __builtin_amdgcn_mfma_f32_16x16x32_bf16(af[mf], bf[nf], acc[mf][nf], 0, 0, 0);
            }
        }
        __syncthreads();
    }

    #pragma unroll
    for (int nf = 0; nf < 4; ++nf){
        const int n = ntile * 128 + wn * 64 + nf * 16 + lr;
        if (n >= VOCAB) continue;
        const float bp = b_pred[n];
        #pragma unroll
        for (int mf = 0; mf < 4; ++mf){
            const int m = mtile * 128 + wm * 64 + mf * 16 + kq * 4;
            #pragma unroll
            for (int q = 0; q < 4; ++q){
                out[(size_t)(m + q) * VOCAB + n] = acc[mf][nf][q] + bp;
            }
        }
    }
}

// ---------------------------------------------------------------------------
extern "C" void kernel_launch(void* const* d_in, const int* in_sizes, int n_in,
                              void* d_out, int out_size, void* d_ws, size_t ws_size,
                              hipStream_t stream){
    const float* x      = (const float*)d_in[0];
    const float* h0     = (const float*)d_in[1];
    const float* w_ih   = (const float*)d_in[2];
    const float* w_hh   = (const float*)d_in[3];
    const float* b_ih   = (const float*)d_in[4];
    const float* b_hh   = (const float*)d_in[5];
    const float* w_pred = (const float*)d_in[6];
    const float* b_pred = (const float*)d_in[7];
    float* out = (float*)d_out;

    float*    xg   = (float*)d_ws;                        // 1024*1536 fp32
    float*    hs   = xg + (size_t)T_STEPS * (3*HDIM);     // 1025*512  fp32
    unsigned* ctrl = (unsigned*)(hs + (size_t)(T_STEPS+1) * HDIM);  // 8 u32

    hipLaunchKernelGGL(init_hs_kernel, dim3(T_STEPS + 1), dim3(HDIM), 0, stream, h0, hs, ctrl);
    hipLaunchKernelGGL(xg_kernel,      dim3(6, 128),      dim3(256),  0, stream, x, w_ih, b_ih, xg);
    hipLaunchKernelGGL(scan_kernel,    dim3(256),         dim3(512),  0, stream, xg, w_hh, b_hh, hs, ctrl);
    hipLaunchKernelGGL(pred_gemm_kernel, dim3(8, 227),    dim3(256),  0, stream, hs, w_pred, b_pred, out);
}